// Round 6
// baseline (164.624 us; speedup 1.0000x reference)
//
#include <hip/hip_runtime.h>

#define IMG_H 512
#define IMG_W 512
#define NPLANES 48            // 16 batch * 3 channels
#define N_ELEMS (16 * 3 * 512 * 512)
#define NTHREADS 256
#define NBLOCKS 12288         // 16x16 tiles x 48 planes
#define LSTR 56               // layout2 row stride in bf16 (48 used; 112B: 16B-aligned, 2-way banks)

#define C1f 1.0e-4f
#define C2f 9.0e-4f

typedef float v4f __attribute__((ext_vector_type(4)));
typedef short v8s __attribute__((ext_vector_type(8)));

// Gaussian band table: G[t] at index 24+t, zeros elsewhere (band masks tile padding).
__device__ __constant__ float GT[64] = {
    0,0,0,0,0,0,0,0,0,0,0,0,0,0,0,0,0,0,0,0,0,0,0,0,
    0.00102838f, 0.00759876f, 0.03600077f, 0.10936070f, 0.21300553f,
    0.26601173f,
    0.21300553f, 0.10936070f, 0.03600077f, 0.00759876f, 0.00102838f,
    0,0,0,0,0,0,0,0,0,0,0,0,0,0,0,0,0,0,0,0,0,0,0,0,0,0,0,0,0
};

// Pack two fp32 -> two bf16 (round-half-up; bias negligible): 3 VALU.
__device__ __forceinline__ unsigned int pk2bf(float x, float y) {
    unsigned int ax = __float_as_uint(x) + 0x8000u;
    unsigned int by = __float_as_uint(y) + 0x8000u;
    return __builtin_amdgcn_perm(by, ax, 0x07060302);  // {ax.hi16, by.hi16}
}

__global__ void __launch_bounds__(NTHREADS, 4) ssim_main(
    const float* __restrict__ img1, const float* __restrict__ img2,
    float* __restrict__ partials)
{
    // Inter-pass buffer: T[(q,xo)][yrow] bf16, rows (q*32+xo), yrow in [0,48).
    __shared__ short T[128 * LSTR];          // 14336 B
    __shared__ float wpart[4];

    const int tid = threadIdx.x;
    const int lane = tid & 63;
    const int wv = tid >> 6;                 // wave id 0..3
    const int m = lane & 15;
    const int qd = lane >> 4;                // quad 0..3

    // XCD swizzle: each XCD gets 6 contiguous planes (L2-resident halos).
    const int work = (blockIdx.x & 7) * (NBLOCKS / 8) + (blockIdx.x >> 3);
    const int plane = work >> 8;
    const int rem = work & 255;
    const int by = rem >> 4, bx = rem & 15;
    const int tx0 = bx * 32, ty0 = by * 32;
    const float* p1 = img1 + (size_t)plane * IMG_H * IMG_W;
    const float* p2 = img2 + (size_t)plane * IMG_H * IMG_W;

    // Constant G-band fragments (bf16), built once per block:
    //   gY: pass-2 A-operand  A[m][k] = G[k-m]
    //   gX: pass-1 B-operand  B[k][n] = G[k-n-3]   (x-window base tx0-8 -> band shift 3)
    v8s gX, gY;
    {
        union { v8s v; unsigned int u[4]; } uy, ux;
#pragma unroll
        for (int i = 0; i < 4; ++i) {
            int k0 = qd * 8 + 2 * i;
            uy.u[i] = pk2bf(GT[24 + k0 - m], GT[25 + k0 - m]);
            ux.u[i] = pk2bf(GT[21 + k0 - m], GT[22 + k0 - m]);
        }
        gY = uy.v; gX = ux.v;
    }

    const bool interior = (bx > 0) & (bx < 15) & (by > 0) & (by < 15);
    const v4f zero4 = {0.f, 0.f, 0.f, 0.f};

    // ---- Pass 1: horizontal conv as banded GEMM, direct-from-global A ----
    // 6 combos (yg 0..2, xoh 0..1); wave w takes combos {w, w+4}.
#pragma unroll
    for (int cc = 0; cc < 2; ++cc) {
        int c = wv + 4 * cc;
        if (c < 6) {
            const int yg = c >> 1, xoh = c & 1;
            const int yrow = yg * 16 + m;                  // lane's y-row [0,48)
            const int gy = ty0 - 5 + yrow;
            const int xb = tx0 - 8 + xoh * 16 + qd * 8;    // 32B-aligned base
            float a[8], b[8];
            if (interior) {
                const float* pa = p1 + (size_t)gy * IMG_W + xb;
                const float* pb = p2 + (size_t)gy * IMG_W + xb;
                *(float4*)&a[0] = *(const float4*)pa;
                *(float4*)&a[4] = *(const float4*)(pa + 4);
                *(float4*)&b[0] = *(const float4*)pb;
                *(float4*)&b[4] = *(const float4*)(pb + 4);
            } else {
                const int gyc = min(max(gy, 0), IMG_H - 1);
                const bool oky = (unsigned)gy < IMG_H;
                const float* ra = p1 + (size_t)gyc * IMG_W;
                const float* rb = p2 + (size_t)gyc * IMG_W;
#pragma unroll
                for (int j = 0; j < 8; ++j) {
                    int gx = xb + j;
                    int gxc = min(max(gx, 0), IMG_W - 1);
                    bool ok = oky && ((unsigned)gx < IMG_W);
                    a[j] = ok ? ra[gxc] : 0.f;
                    b[j] = ok ? rb[gxc] : 0.f;
                }
            }
            // Quantities s,d,s^2,d^2 -> bf16 A-fragments.
            union { v8s v; unsigned int u[4]; } fs, fd, fss, fdd;
#pragma unroll
            for (int i = 0; i < 4; ++i) {
                float s0 = a[2*i] + b[2*i], s1 = a[2*i+1] + b[2*i+1];
                float d0 = a[2*i] - b[2*i], d1 = a[2*i+1] - b[2*i+1];
                fs.u[i]  = pk2bf(s0, s1);
                fd.u[i]  = pk2bf(d0, d1);
                fss.u[i] = pk2bf(s0 * s0, s1 * s1);
                fdd.u[i] = pk2bf(d0 * d0, d1 * d1);
            }
            v4f t0 = __builtin_amdgcn_mfma_f32_16x16x32_bf16(fs.v,  gX, zero4, 0, 0, 0);
            v4f t1 = __builtin_amdgcn_mfma_f32_16x16x32_bf16(fd.v,  gX, zero4, 0, 0, 0);
            v4f t2 = __builtin_amdgcn_mfma_f32_16x16x32_bf16(fss.v, gX, zero4, 0, 0, 0);
            v4f t3 = __builtin_amdgcn_mfma_f32_16x16x32_bf16(fdd.v, gX, zero4, 0, 0, 0);
            // C-layout: col xo = xoh*16 + m (lane&15), rows yrow0..+3 = yg*16 + qd*4 + r
            // -> 4 consecutive y at fixed xo: ONE ds_write_b64 per quantity.
            const int ybase = yg * 16 + qd * 4;
            const int rbase = xoh * 16 + m;
            *(uint2*)&T[(0 * 32 + rbase) * LSTR + ybase] =
                make_uint2(pk2bf(t0[0], t0[1]), pk2bf(t0[2], t0[3]));
            *(uint2*)&T[(1 * 32 + rbase) * LSTR + ybase] =
                make_uint2(pk2bf(t1[0], t1[1]), pk2bf(t1[2], t1[3]));
            *(uint2*)&T[(2 * 32 + rbase) * LSTR + ybase] =
                make_uint2(pk2bf(t2[0], t2[1]), pk2bf(t2[2], t2[3]));
            *(uint2*)&T[(3 * 32 + rbase) * LSTR + ybase] =
                make_uint2(pk2bf(t3[0], t3[1]), pk2bf(t3[2], t3[3]));
        }
    }
    __syncthreads();

    // ---- Pass 2: vertical conv as banded GEMM. Wave -> (yo-half, xo-half). ----
    const int yh = wv >> 1, xh = wv & 1;
    v4f acc[4];
#pragma unroll
    for (int q = 0; q < 4; ++q) {
        const int off = (q * 32 + xh * 16 + m) * LSTR + yh * 16 + qd * 8;
        v8s tf = *(const v8s*)&T[off];                    // ds_read_b128, 16B-aligned
        acc[q] = __builtin_amdgcn_mfma_f32_16x16x32_bf16(gY, tf, zero4, 0, 0, 0);
    }

    // ---- Epilogue: each lane has (cs,cd,css,cdd) for 4 output px in-register ----
    float local = 0.f;
#pragma unroll
    for (int r = 0; r < 4; ++r) {
        float cs = acc[0][r], cd = acc[1][r];
        float css = acc[2][r], cdd = acc[3][r];
        float cs2 = cs * cs, cd2 = cd * cd;
        float mu12 = 0.25f * (cs2 - cd2);     // mu1*mu2
        float musq = 0.50f * (cs2 + cd2);     // mu1^2 + mu2^2
        float e12  = 0.25f * (css - cdd);     // E[ab]
        float esum = 0.50f * (css + cdd);     // E[a^2] + E[b^2]
        float sg12  = e12 - mu12;
        float sgsum = esum - musq;
        float num = (2.f * mu12 + C1f) * (2.f * sg12 + C2f);
        float den = (musq + C1f) * (sgsum + C2f);
        local += num * __builtin_amdgcn_rcpf(den);
    }

    // ---- Block reduction -> one partial per block ----
#pragma unroll
    for (int off = 32; off > 0; off >>= 1) local += __shfl_down(local, off, 64);
    if (lane == 0) wpart[wv] = local;
    __syncthreads();
    if (tid == 0)
        partials[blockIdx.x] = wpart[0] + wpart[1] + wpart[2] + wpart[3];
}

__global__ void ssim_final(const float* __restrict__ partials,
                           float* __restrict__ out)
{
    __shared__ float wp[4];
    const int tid = threadIdx.x;
    const float4* p4 = (const float4*)partials;      // 3072 float4
    float s = 0.0f;
#pragma unroll
    for (int k = 0; k < 12; ++k) {
        float4 v = p4[tid + k * NTHREADS];
        s += (v.x + v.y) + (v.z + v.w);
    }
#pragma unroll
    for (int off = 32; off > 0; off >>= 1) s += __shfl_down(s, off, 64);
    if ((tid & 63) == 0) wp[tid >> 6] = s;
    __syncthreads();
    if (tid == 0)
        out[0] = 1.0f - (wp[0] + wp[1] + wp[2] + wp[3]) * (1.0f / (float)N_ELEMS);
}

extern "C" void kernel_launch(void* const* d_in, const int* in_sizes, int n_in,
                              void* d_out, int out_size, void* d_ws, size_t ws_size,
                              hipStream_t stream) {
    const float* img1 = (const float*)d_in[0];
    const float* img2 = (const float*)d_in[1];
    float* out = (float*)d_out;
    float* partials = (float*)d_ws;     // NBLOCKS floats = 48 KB

    ssim_main<<<NBLOCKS, NTHREADS, 0, stream>>>(img1, img2, partials);
    ssim_final<<<1, NTHREADS, 0, stream>>>(partials, out);
}

// Round 7
// 155.644 us; speedup vs baseline: 1.0577x; 1.0577x over previous
//
#include <hip/hip_runtime.h>

#define IMG_H 512
#define IMG_W 512
#define N_ELEMS (16 * 3 * 512 * 512)
#define NTHREADS 256
#define NBLK 1024             // persistent-ish: 4 blocks/CU, 12 tiles each
#define ITERS 6               // 2 adjacent tiles (64x32 region) per iteration
#define LSTR 56               // T col stride (48 used; 112B rows -> 2-way banks = free)

#define C1f 1.0e-4f
#define C2f 9.0e-4f

typedef float v4f __attribute__((ext_vector_type(4)));
typedef short v8s __attribute__((ext_vector_type(8)));

// Gaussian band table: G[t] at index 24+t, zeros elsewhere (band masks padding).
__device__ __constant__ float GT[64] = {
    0,0,0,0,0,0,0,0,0,0,0,0,0,0,0,0,0,0,0,0,0,0,0,0,
    0.00102838f, 0.00759876f, 0.03600077f, 0.10936070f, 0.21300553f,
    0.26601173f,
    0.21300553f, 0.10936070f, 0.03600077f, 0.00759876f, 0.00102838f,
    0,0,0,0,0,0,0,0,0,0,0,0,0,0,0,0,0,0,0,0,0,0,0,0,0,0,0,0,0
};

// Pack two fp32 -> two bf16 (round-half-up): 3 VALU. (Verified in round 6.)
__device__ __forceinline__ unsigned int pk2bf(float x, float y) {
    unsigned int ax = __float_as_uint(x) + 0x8000u;
    unsigned int by = __float_as_uint(y) + 0x8000u;
    return __builtin_amdgcn_perm(by, ax, 0x07060302);
}

__global__ void __launch_bounds__(NTHREADS, 4) ssim_main(
    const float* __restrict__ img1, const float* __restrict__ img2,
    float* __restrict__ partials)
{
    // T: per-wave private scratch (wave wv owns rows [wv*16, wv*16+16) mod 64).
    // rows = q*64 + xh*16 + m (q=quantity, xh=x-half=wave), cols = y in [0,48).
    __shared__ short T[256 * LSTR];          // 28672 B
    __shared__ float wpart[4];

    const int tid = threadIdx.x;
    const int lane = tid & 63;
    const int wv = tid >> 6;                 // wave id = x-half owned
    const int m = lane & 15;
    const int qd = lane >> 4;

    // G-band fragments (built ONCE per block, amortized over 12 tiles):
    //   gY: pass-2 A-operand  A[m][k] = G[k-m]
    //   gX: pass-1 B-operand  B[k][n] = G[k-n-3]
    v8s gX, gY;
    {
        union { v8s v; unsigned int u[4]; } uy, ux;
#pragma unroll
        for (int i = 0; i < 4; ++i) {
            int k0 = qd * 8 + 2 * i;
            uy.u[i] = pk2bf(GT[24 + k0 - m], GT[25 + k0 - m]);
            ux.u[i] = pk2bf(GT[21 + k0 - m], GT[22 + k0 - m]);
        }
        gY = uy.v; gX = ux.v;
    }

    // XCD-local work range: XCD (blockIdx&7) owns 6 contiguous planes.
    const int wbase = (blockIdx.x & 7) * 1536 + (blockIdx.x >> 3) * 12;
    const v4f zero4 = {0.f, 0.f, 0.f, 0.f};
    float local = 0.f;

    for (int it = 0; it < ITERS; ++it) {
        const int w = wbase + 2 * it;            // even -> pair never straddles a row
        const int plane = w >> 8;
        const int rem = w & 255;
        const int ty0 = (rem >> 4) * 32;
        const int tx0 = (rem & 15) * 32;         // pair covers x [tx0, tx0+64)
        const float* p1 = img1 + (size_t)plane * IMG_H * IMG_W;
        const float* p2 = img2 + (size_t)plane * IMG_H * IMG_W;

        const int xb_lo = tx0 - 8 + wv * 16;     // this wave's 32-wide K-window
        const bool okx = (xb_lo >= 0) && (xb_lo + 32 <= IMG_W);

        // ---- Pass 1: horizontal banded GEMM, 3 y-groups, all waves balanced ----
#pragma unroll
        for (int yg = 0; yg < 3; ++yg) {
            const int gy = ty0 - 5 + yg * 16 + m;
            const int xb = xb_lo + qd * 8;
            float a[8], b[8];
            const bool fast = okx && (ty0 - 5 + yg * 16 >= 0) &&
                              (ty0 + yg * 16 + 10 < IMG_H);       // wave-uniform
            if (fast) {
                const float* pa = p1 + (size_t)gy * IMG_W + xb;
                const float* pb = p2 + (size_t)gy * IMG_W + xb;
                *(float4*)&a[0] = *(const float4*)pa;
                *(float4*)&a[4] = *(const float4*)(pa + 4);
                *(float4*)&b[0] = *(const float4*)pb;
                *(float4*)&b[4] = *(const float4*)(pb + 4);
            } else {
                const int gyc = min(max(gy, 0), IMG_H - 1);
                const bool oky = (unsigned)gy < IMG_H;
                const float* ra = p1 + (size_t)gyc * IMG_W;
                const float* rb = p2 + (size_t)gyc * IMG_W;
#pragma unroll
                for (int j = 0; j < 8; ++j) {
                    int gx = xb + j;
                    int gxc = min(max(gx, 0), IMG_W - 1);
                    bool ok = oky && ((unsigned)gx < IMG_W);
                    a[j] = ok ? ra[gxc] : 0.f;
                    b[j] = ok ? rb[gxc] : 0.f;
                }
            }
            union { v8s v; unsigned int u[4]; } fs, fd, fss, fdd;
#pragma unroll
            for (int i = 0; i < 4; ++i) {
                float s0 = a[2*i] + b[2*i], s1 = a[2*i+1] + b[2*i+1];
                float d0 = a[2*i] - b[2*i], d1 = a[2*i+1] - b[2*i+1];
                fs.u[i]  = pk2bf(s0, s1);
                fd.u[i]  = pk2bf(d0, d1);
                fss.u[i] = pk2bf(s0 * s0, s1 * s1);
                fdd.u[i] = pk2bf(d0 * d0, d1 * d1);
            }
            v4f t0 = __builtin_amdgcn_mfma_f32_16x16x32_bf16(fs.v,  gX, zero4, 0, 0, 0);
            v4f t1 = __builtin_amdgcn_mfma_f32_16x16x32_bf16(fd.v,  gX, zero4, 0, 0, 0);
            v4f t2 = __builtin_amdgcn_mfma_f32_16x16x32_bf16(fss.v, gX, zero4, 0, 0, 0);
            v4f t3 = __builtin_amdgcn_mfma_f32_16x16x32_bf16(fdd.v, gX, zero4, 0, 0, 0);
            // C-layout: col xo = m, rows y = yg*16 + qd*4 + r -> one b64/quantity.
            const int ybase = yg * 16 + qd * 4;
            const int rbase = wv * 16 + m;
            *(uint2*)&T[(0 * 64 + rbase) * LSTR + ybase] =
                make_uint2(pk2bf(t0[0], t0[1]), pk2bf(t0[2], t0[3]));
            *(uint2*)&T[(1 * 64 + rbase) * LSTR + ybase] =
                make_uint2(pk2bf(t1[0], t1[1]), pk2bf(t1[2], t1[3]));
            *(uint2*)&T[(2 * 64 + rbase) * LSTR + ybase] =
                make_uint2(pk2bf(t2[0], t2[1]), pk2bf(t2[2], t2[3]));
            *(uint2*)&T[(3 * 64 + rbase) * LSTR + ybase] =
                make_uint2(pk2bf(t3[0], t3[1]), pk2bf(t3[2], t3[3]));
        }

        // ---- Pass 2: vertical banded GEMM on OWN wave's T rows -> no barrier ----
#pragma unroll
        for (int yh = 0; yh < 2; ++yh) {
            v4f acc[4];
#pragma unroll
            for (int q = 0; q < 4; ++q) {
                const int off = (q * 64 + wv * 16 + m) * LSTR + yh * 16 + qd * 8;
                v8s tf = *(const v8s*)&T[off];            // ds_read_b128 (aligned)
                acc[q] = __builtin_amdgcn_mfma_f32_16x16x32_bf16(gY, tf, zero4, 0, 0, 0);
            }
#pragma unroll
            for (int r = 0; r < 4; ++r) {
                float cs = acc[0][r], cd = acc[1][r];
                float css = acc[2][r], cdd = acc[3][r];
                float cs2 = cs * cs, cd2 = cd * cd;
                float mu12 = 0.25f * (cs2 - cd2);
                float musq = 0.50f * (cs2 + cd2);
                float e12  = 0.25f * (css - cdd);
                float esum = 0.50f * (css + cdd);
                float sg12  = e12 - mu12;
                float sgsum = esum - musq;
                float num = (2.f * mu12 + C1f) * (2.f * sg12 + C2f);
                float den = (musq + C1f) * (sgsum + C2f);
                local += num * __builtin_amdgcn_rcpf(den);
            }
        }
    }

    // ---- One reduction per block (the only barrier in the kernel) ----
#pragma unroll
    for (int off = 32; off > 0; off >>= 1) local += __shfl_down(local, off, 64);
    if (lane == 0) wpart[wv] = local;
    __syncthreads();
    if (tid == 0)
        partials[blockIdx.x] = wpart[0] + wpart[1] + wpart[2] + wpart[3];
}

__global__ void ssim_final(const float* __restrict__ partials,
                           float* __restrict__ out)
{
    __shared__ float wp[4];
    const int tid = threadIdx.x;
    float4 v = ((const float4*)partials)[tid];       // 1024 floats = 256 float4
    float s = (v.x + v.y) + (v.z + v.w);
#pragma unroll
    for (int off = 32; off > 0; off >>= 1) s += __shfl_down(s, off, 64);
    if ((tid & 63) == 0) wp[tid >> 6] = s;
    __syncthreads();
    if (tid == 0)
        out[0] = 1.0f - (wp[0] + wp[1] + wp[2] + wp[3]) * (1.0f / (float)N_ELEMS);
}

extern "C" void kernel_launch(void* const* d_in, const int* in_sizes, int n_in,
                              void* d_out, int out_size, void* d_ws, size_t ws_size,
                              hipStream_t stream) {
    const float* img1 = (const float*)d_in[0];
    const float* img2 = (const float*)d_in[1];
    float* out = (float*)d_out;
    float* partials = (float*)d_ws;     // NBLK floats = 4 KB

    ssim_main<<<NBLK, NTHREADS, 0, stream>>>(img1, img2, partials);
    ssim_final<<<1, NTHREADS, 0, stream>>>(partials, out);
}